// Round 8
// baseline (51.086 us; speedup 1.0000x reference)
//
#include <hip/hip_runtime.h>
#include <stdint.h>

#define NUM_PIDS 20000
#define HBLK_MAX 128           // histogram partial tables (one per hist block)
#define NCH      8             // reduce stage-1 fan-in chunks
#define FIXB     512.0f        // 2^9 fixed point for per-hit mse (17-bit field)
#define FXMASK   0x1FFFFu
#define CHUNK    256           // hits per block-chunk (64 per wave)
#define MSE_NBLK 1280          // 5 blocks/CU at 32 KB LDS
// packed u32 per hit: pid in bits[17:31], fx in bits[0:16]; 0 = excluded hit
// LDS / tbl cell: count in bits[24:31], fx-sum in bits[0:23]
// tmp u64: count in bits[40:63], fx-sum in bits[0:39]

// ws: [ u32 packed[n] | u32 tbl[hblk][NUM_PIDS] | u64 tmp[NCH][NUM_PIDS] | float acc[2] ]

__global__ void zero_acc_kernel(float* __restrict__ acc) {
    if (threadIdx.x < 2) acc[threadIdx.x] = 0.0f;
}

__device__ __forceinline__ unsigned int pack_hit(unsigned int p, unsigned int r, float mse) {
    unsigned int fx = (unsigned int)fminf(mse * FIXB + 0.5f, 131071.0f);
    return ((int)p > 0 && (int)r > 0) ? ((p << 17) | fx) : 0u;
}

// direct-to-LDS DMA: global src is per-lane, LDS dst is wave-uniform base
// (HW adds lane*16) [m104]. Layout linear -> matches global byte order.
#define GLDS16(g, l) __builtin_amdgcn_global_load_lds( \
    (const __attribute__((address_space(1))) void*)(g), \
    (__attribute__((address_space(3))) void*)(l), 16, 0, 0)

// counted wait + compiler fence (rule #18: sched_barrier after asm waitcnt)
#define WAITV(N) do { \
    asm volatile("s_waitcnt vmcnt(" #N ")" ::: "memory"); \
    __builtin_amdgcn_sched_barrier(0); } while (0)

__global__ void __launch_bounds__(256) mse_kernel(
        const char* __restrict__ predG,
        const char* __restrict__ trackG,
        const char* __restrict__ pidG,
        const char* __restrict__ recG,
        unsigned int* __restrict__ packed,
        int n) {
    // two buffers, statically named (rule #20); 4 x 8 KB = 32 KB
    __shared__ float4 P0[CHUNK * 2], T0[CHUNK * 2];
    __shared__ float4 P1[CHUNK * 2], T1[CHUNK * 2];

    const int w = threadIdx.x >> 6;        // wave id (uniform per wave)
    const int l = threadIdx.x & 63;        // lane
    const long nfull = n / CHUNK;
    const long stride = gridDim.x;

    // stage chunk c into (PB,TB): 4 glLDS (2 KB pred + 2 KB track per wave,
    // this wave's own 64-hit slice) + 2 asm dword loads. 6 vm ops, hand-ordered.
#define STAGE(PB, TB, c, pReg, rReg) do { \
        long base_ = (long)(c) * (CHUNK * 32) + (long)w * 2048; \
        const char* gp_ = predG + base_ + (long)l * 16; \
        const char* gt_ = trackG + base_ + (long)l * 16; \
        char* dp_ = (char*)(PB) + w * 2048; \
        char* dt_ = (char*)(TB) + w * 2048; \
        GLDS16(gp_,        dp_); \
        GLDS16(gp_ + 1024, dp_ + 1024); \
        GLDS16(gt_,        dt_); \
        GLDS16(gt_ + 1024, dt_ + 1024); \
        long hit_ = (long)(c) * CHUNK + w * 64 + l; \
        asm volatile("global_load_dword %0, %2, off\n\t" \
                     "global_load_dword %1, %3, off" \
                     : "=&v"(pReg), "=&v"(rReg) \
                     : "v"(pidG + hit_ * 4), "v"(recG + hit_ * 4) \
                     : "memory"); \
    } while (0)

#define CONSUME(PB, TB, c, pReg, rReg) do { \
        int h_ = w * 64 + l; \
        float4 a0_ = (PB)[2 * h_], a1_ = (PB)[2 * h_ + 1]; \
        float4 b0_ = (TB)[2 * h_], b1_ = (TB)[2 * h_ + 1]; \
        float d0_ = a0_.x - b0_.x, d1_ = a0_.y - b0_.y; \
        float d2_ = a0_.z - b0_.z, d3_ = a0_.w - b0_.w; \
        float d4_ = a1_.x - b1_.x, d5_ = a1_.y - b1_.y; \
        float d6_ = a1_.z - b1_.z, d7_ = a1_.w - b1_.w; \
        float m_ = d0_*d0_ + d1_*d1_ + d2_*d2_ + d3_*d3_ \
                 + d4_*d4_ + d5_*d5_ + d6_*d6_ + d7_*d7_; \
        packed[(long)(c) * CHUNK + h_] = pack_hit(pReg, rReg, m_); \
    } while (0)

    long c = blockIdx.x;
    unsigned int pA, rA, pB, rB;
    if (c < nfull) {
        STAGE(P0, T0, c, pA, rA);
        for (;;) {
            long cn = c + stride;
            if (cn < nfull) { STAGE(P1, T1, cn, pB, rB); WAITV(6); }
            else WAITV(0);
            CONSUME(P0, T0, c, pA, rA);
            if (cn >= nfull) break;
            c = cn;
            cn = c + stride;
            if (cn < nfull) { STAGE(P0, T0, cn, pA, rA); WAITV(6); }
            else WAITV(0);
            CONSUME(P1, T1, c, pB, rB);
            if (cn >= nfull) break;
            c = cn;
        }
    }
    // tail hits [nfull*CHUNK, n): plain predicated loads, block 0 only
    if (blockIdx.x == 0) {
        for (long h = nfull * CHUNK + threadIdx.x; h < n; h += 256) {
            const float4* pa = (const float4*)(predG + h * 32);
            const float4* pb = (const float4*)(trackG + h * 32);
            float4 a0 = pa[0], a1 = pa[1], b0 = pb[0], b1 = pb[1];
            float d0 = a0.x-b0.x, d1 = a0.y-b0.y, d2 = a0.z-b0.z, d3 = a0.w-b0.w;
            float d4 = a1.x-b1.x, d5 = a1.y-b1.y, d6 = a1.z-b1.z, d7 = a1.w-b1.w;
            float m = d0*d0+d1*d1+d2*d2+d3*d3 + d4*d4+d5*d5+d6*d6+d7*d7;
            packed[h] = pack_hit(((const unsigned int*)pidG)[h],
                                 ((const unsigned int*)recG)[h], m);
        }
    }
#undef STAGE
#undef CONSUME
}

__global__ void __launch_bounds__(1024) hist_kernel(
        const uint4* __restrict__ packed4,
        unsigned int* __restrict__ tbl,
        int n4,
        const unsigned int* __restrict__ packed,
        int n) {
    __shared__ unsigned int bins[NUM_PIDS];        // 80 KB -> 2 blocks/CU
    for (int j = threadIdx.x; j < NUM_PIDS; j += 1024) bins[j] = 0u;
    __syncthreads();
    int t = blockIdx.x * 1024 + threadIdx.x;
    int stride = gridDim.x * 1024;
    for (; t < n4; t += stride) {
        uint4 v = packed4[t];
        unsigned int p;
        p = v.x >> 17; if (p) atomicAdd(&bins[p], (1u << 24) | (v.x & FXMASK));
        p = v.y >> 17; if (p) atomicAdd(&bins[p], (1u << 24) | (v.y & FXMASK));
        p = v.z >> 17; if (p) atomicAdd(&bins[p], (1u << 24) | (v.z & FXMASK));
        p = v.w >> 17; if (p) atomicAdd(&bins[p], (1u << 24) | (v.w & FXMASK));
    }
    for (int i = 4 * n4 + blockIdx.x * 1024 + threadIdx.x; i < n; i += stride) {
        unsigned int c = packed[i];
        unsigned int p = c >> 17;
        if (p) atomicAdd(&bins[p], (1u << 24) | (c & FXMASK));
    }
    __syncthreads();
    unsigned int* my = tbl + (size_t)blockIdx.x * NUM_PIDS;
    for (int j = threadIdx.x; j < NUM_PIDS; j += 1024) my[j] = bins[j];
}

// stage 1: sum a chunk of block-tables into u64 tmp[chunk][pid]
__global__ void __launch_bounds__(256) reduce1_kernel(
        const unsigned int* __restrict__ tbl,
        unsigned long long* __restrict__ tmp,
        int nblk) {
    int p = blockIdx.x * 256 + threadIdx.x;
    int c = blockIdx.y;
    if (p >= NUM_PIDS) return;
    int cs = (nblk + NCH - 1) / NCH;
    int b0 = c * cs, b1 = min(nblk, b0 + cs);
    unsigned long long sfx = 0ULL, cnt = 0ULL;
    for (int b = b0; b < b1; ++b) {
        unsigned int v = tbl[(size_t)b * NUM_PIDS + p];   // coalesced
        sfx += (unsigned long long)(v & 0xFFFFFFu);
        cnt += (unsigned long long)(v >> 24);
    }
    tmp[(size_t)c * NUM_PIDS + p] = (cnt << 40) | sfx;
}

// stage 2: fold NCH chunks, per-pid mean, block-reduce, 2 atomics/block
__global__ void __launch_bounds__(256) reduce2_kernel(
        const unsigned long long* __restrict__ tmp,
        float* __restrict__ acc) {
    int p = blockIdx.x * 256 + threadIdx.x;
    float mean = 0.0f, pres = 0.0f;
    if (p >= 1 && p < NUM_PIDS) {
        unsigned long long s = 0ULL;
        #pragma unroll
        for (int c = 0; c < NCH; ++c) s += tmp[(size_t)c * NUM_PIDS + p];
        unsigned long long cnt = s >> 40;
        if (cnt > 0) {
            double sum = (double)(s & ((1ULL << 40) - 1)) * (1.0 / 512.0);
            mean = (float)(sum / (double)cnt);
            pres = 1.0f;
        }
    }
    #pragma unroll
    for (int off = 32; off > 0; off >>= 1) {
        mean += __shfl_down(mean, off);
        pres += __shfl_down(pres, off);
    }
    __shared__ float smean[4], spres[4];
    int wave = threadIdx.x >> 6, lane = threadIdx.x & 63;
    if (lane == 0) { smean[wave] = mean; spres[wave] = pres; }
    __syncthreads();
    if (threadIdx.x == 0) {
        atomicAdd(&acc[0], smean[0] + smean[1] + smean[2] + smean[3]);
        atomicAdd(&acc[1], spres[0] + spres[1] + spres[2] + spres[3]);
    }
}

__global__ void final_kernel(const float* __restrict__ acc,
                             float* __restrict__ out) {
    if (threadIdx.x == 0 && blockIdx.x == 0) {
        float K = acc[1];
        out[0] = (K > 0.0f) ? (100.0f * acc[0] / K) : 0.0f;
    }
}

extern "C" void kernel_launch(void* const* d_in, const int* in_sizes, int n_in,
                              void* d_out, int out_size, void* d_ws, size_t ws_size,
                              hipStream_t stream) {
    // setup_inputs order: W(0) beta(1) H(2) pred(3) Y(4) particle_id(5)
    //                     track_params(6) reconstructable(7)
    const char* pred  = (const char*)d_in[3];
    const char* pid   = (const char*)d_in[5];
    const char* track = (const char*)d_in[6];
    const char* recon = (const char*)d_in[7];
    int n = in_sizes[5];   // N hits

    size_t packed_bytes = (((size_t)n * 4) + 63) & ~(size_t)63;
    size_t tmp_bytes = (size_t)NCH * NUM_PIDS * 8;
    // adaptive histogram-table count
    int hblk = 8;
    if (ws_size > packed_bytes + tmp_bytes + 64 + (size_t)NUM_PIDS * 4) {
        size_t cap = (ws_size - packed_bytes - tmp_bytes - 64) / ((size_t)NUM_PIDS * 4);
        hblk = (int)(cap < HBLK_MAX ? cap : HBLK_MAX);
        if (hblk < 1) hblk = 1;
    }

    unsigned int* packed = (unsigned int*)d_ws;
    unsigned int* tbl = (unsigned int*)((char*)d_ws + packed_bytes);
    unsigned long long* tmp =
        (unsigned long long*)((char*)tbl + (size_t)hblk * NUM_PIDS * 4);
    float* acc = (float*)((char*)tmp + tmp_bytes);

    int nb = MSE_NBLK;
    long nfull = n / CHUNK;
    if (nfull > 0 && nfull < nb) nb = (int)nfull;
    if (nb < 1) nb = 1;

    zero_acc_kernel<<<1, 64, 0, stream>>>(acc);
    mse_kernel<<<nb, 256, 0, stream>>>(pred, track, pid, recon, packed, n);
    hist_kernel<<<hblk, 1024, 0, stream>>>((const uint4*)packed, tbl, n / 4,
                                           packed, n);
    dim3 g1((NUM_PIDS + 255) / 256, NCH);
    reduce1_kernel<<<g1, 256, 0, stream>>>(tbl, tmp, hblk);
    reduce2_kernel<<<(NUM_PIDS + 255) / 256, 256, 0, stream>>>(tmp, acc);
    final_kernel<<<1, 64, 0, stream>>>(acc, (float*)d_out);
}